// Round 1
// 156.428 us; speedup vs baseline: 1.1025x; 1.1025x over previous
//
#include <hip/hip_runtime.h>
#include <string.h>

// Integer-quantized MHA. Phase 1: exact-int i8 K=64 MFMA digit GEMM. Phase 2:
// native bf16 MFMA (r_q<=255, vt mantissa 8-bit -> exact products).
// R7 changes vs R6 (172us, mha=86us, VALUBusy 61%):
//  - digitize rewritten gather-style: one wave per output fragment tile, lane i
//    stores base+i*16 -> fully coalesced 1KB wave-stores (old vd path had 8KB
//    lane stride = 4x write amplification; digitize was ~half the total time).
//  - softmax in log2 domain: one fused CS2=CS*log2e scale (stored back into scv
//    as f32 bits), row max/sum unchanged, exp via bare v_exp_f32 (inline asm)
//    instead of library expf.
//  - group-of-8 requant restructured: group == one rbuf granule (8 consecutive
//    8-aligned S-cols = the 16B phase-2 A-fragment). Write RAW u16 probs to
//    rbuf, barrier, then each thread requants 8 granules in-register in-place
//    (b128 ld -> max tree -> po2 shift -> bf16 -> b128 st). Removes 192
//    ds_bpermute (shfl_xor) + ~300 VALU per thread.
// B=2,H=16 (BH=32), T=S=1024, HC=128, G=8. Output int32.

typedef int   v4i __attribute__((ext_vector_type(4)));
typedef float v4f __attribute__((ext_vector_type(4)));
typedef short v8s __attribute__((ext_vector_type(8)));

#define BHN 32
#define TN  1024
#define SN  1024
#define HCN 128
#define TT  16
#define RST 1032               // rbuf row stride (u16): 2064 B == 16 mod 128 -> conflict-free
#define KD_BH 262144           // 8 chunks * 32 KB (2 planes, fragment-ordered)
#define VD_BH 262144           // 32 kb * 8 n * 64 lanes * 16 B (bf16 frags)
#define WS_NEED ((size_t)BHN*(KD_BH+VD_BH))   // 16 MB

__device__ __forceinline__ unsigned pack_b(int b0,int b1,int b2,int b3){
    return (unsigned)((b0&255)|((b1&255)<<8)|((b2&255)<<16)|((b3&255)<<24));
}

// digitize 16 consecutive dequantized ints (2 scale groups) into hi/lo i8 digit vectors
__device__ __forceinline__ void dig16(const int* __restrict__ p, int s0, int s1,
                                      v4i& hi, v4i& lo){
    #pragma unroll
    for (int wi=0; wi<4; ++wi){
        v4i m = *(const v4i*)(p + wi*4);
        int s = (wi<2) ? s0 : s1;
        int d0=m[0]<<s, d1=m[1]<<s, d2=m[2]<<s, d3=m[3]<<s;
        hi[wi] = (int)pack_b(d0>>4,d1>>4,d2>>4,d3>>4);
        lo[wi] = (int)pack_b(d0&15,d1&15,d2&15,d3&15);
    }
}

__device__ __forceinline__ unsigned short bf16_of_int(int v){
    return (unsigned short)(__float_as_uint((float)v) >> 16);   // exact: <=8 sig bits
}

// ---------------- pre-pass (gather form: coalesced stores) ----------------
// kd: per bh, [ch(8)][n(8)][kc(2)][plane(2:hi,lo)][lane64][16B]
// vd: per bh, [kb(32)][n(8)][lane64][16B]  (8 bf16 per lane)
// One wave per fragment tile: wave stores lane*16 -> contiguous 1KB per store.
// Tasks: 0..4095 = kd (bh*128+ch*16+n*2+kc); 4096..12287 = vd (bh*256+kb*8+n).
__global__ __launch_bounds__(256) void digitize(
    const int* __restrict__ k_q, const int* __restrict__ k_s,
    const int* __restrict__ vt_q, const int* __restrict__ vt_s,
    unsigned char* __restrict__ kd, unsigned char* __restrict__ vd)
{
    const int w    = threadIdx.x >> 6;
    const int lane = threadIdx.x & 63;
    const int l15  = lane & 15;
    const int task = blockIdx.x*4 + w;
    if (task < 4096){
        const int kc = task & 1, n = (task>>1)&7, ch = (task>>4)&7, bh = task>>7;
        const int q4   = lane >> 4;
        const int srow = bh*SN + ch*128 + n*16 + l15;
        const int gb   = srow*16 + kc*8 + q4*2;
        v4i hi, lo;
        dig16(k_q + (size_t)srow*HCN + kc*64 + q4*16, k_s[gb], k_s[gb+1], hi, lo);
        size_t base = (size_t)bh*KD_BH + (size_t)(ch*32768 + n*4096 + kc*2048 + lane*16);
        *(v4i*)(kd + base)        = hi;     // 1KB coalesced wave store (hi plane)
        *(v4i*)(kd + base + 1024) = lo;     // 1KB coalesced wave store (lo plane)
    } else {
        const int t  = task - 4096;
        const int n  = t & 7, kb = (t>>3)&31, bh = t>>8;
        const int sub = lane >> 4;                 // s-quad within fragment
        const int row = bh*HCN + n*16 + l15;       // vt channel row
        const int* vp = vt_q + (size_t)row*SN + kb*32 + sub*8;
        const int s   = vt_s[row*128 + kb*4 + sub];
        unsigned wds[4];
        #pragma unroll
        for (int j=0;j<4;j++){
            int a = vp[j*2]   << s;
            int b = vp[j*2+1] << s;
            wds[j] = (unsigned)bf16_of_int(a) | ((unsigned)bf16_of_int(b) << 16);
        }
        size_t base = (size_t)bh*VD_BH + (size_t)(((kb*8 + n)*64 + lane)*16);
        *(v4i*)(vd + base) = v4i{(int)wds[0],(int)wds[1],(int)wds[2],(int)wds[3]};
    }
}

// ---------------- main fused kernel ----------------
template<bool PK>
__global__ __launch_bounds__(256,4) void mha_mfma(
    const int* __restrict__ q_q, const int* __restrict__ q_s,
    const int* __restrict__ k_q, const int* __restrict__ k_s,
    const int* __restrict__ vt_q, const int* __restrict__ vt_s,
    const unsigned char* __restrict__ kd, const unsigned char* __restrict__ vd,
    int* __restrict__ out)
{
    __shared__ __align__(16) unsigned short rbuf[16*RST];  // 33 KB r values, granule swizzle
    __shared__ float red[128];                             // cross-wave softmax reductions

    const int tid  = threadIdx.x;
    const int ln   = tid & 15;
    const int qd4  = (tid >> 4) & 3;
    const int w    = tid >> 6;
    const int lane = tid & 63;
    // XCD-aware swizzle: each XCD's share covers only 4 bh -> digit images fit its L2.
    const int blk = blockIdx.x;
    const int bh  = ((blk>>9)<<3) | (blk&7);
    const int t0  = ((blk>>3)&63) * TT;

    // ---- Q A-fragments in registers (digitized in-reg from global) ----
    v4i qfh[2], qfl[2];
    {
        const int* qrow  = q_q + (size_t)(bh*TN + t0 + ln)*HCN;
        const int* qsrow = q_s + (size_t)(bh*TN + t0 + ln)*16;
        #pragma unroll
        for (int kc=0; kc<2; ++kc){
            int gi = kc*8 + qd4*2;
            dig16(qrow + kc*64 + qd4*16, qsrow[gi], qsrow[gi+1], qfh[kc], qfl[kc]);
        }
    }

    int scv[16][4];   // scores / f32 bits, MFMA C-layout: row=qd4*4+r, col=tile*16+ln

    // ================= phase 1: QK scores (barrier-free, exact int) =================
    const v4i* kb_ = (const v4i*)(kd + (size_t)bh*KD_BH);
    for (int ch=0; ch<8; ++ch){
        #pragma unroll
        for (int i=0;i<2;i++){
            const int n = w*2 + i;
            v4i a2{0,0,0,0}, a1{0,0,0,0}, a0{0,0,0,0};
            #pragma unroll
            for (int kc=0;kc<2;kc++){
                v4i bhv, blv;
                if (PK){
                    const v4i* tb = kb_ + (ch*8+n)*256 + kc*128 + lane;
                    bhv = tb[0];
                    blv = tb[64];
                } else {
                    int srow = bh*SN + ch*128 + n*16 + ln;
                    int cc   = kc*64 + qd4*16;
                    dig16(k_q + (size_t)srow*128 + cc,
                          k_s[srow*16 + (cc>>3)], k_s[srow*16 + (cc>>3) + 1], bhv, blv);
                }
                a2 = __builtin_amdgcn_mfma_i32_16x16x64_i8(qfh[kc], bhv, a2, 0,0,0);
                a1 = __builtin_amdgcn_mfma_i32_16x16x64_i8(qfl[kc], bhv, a1, 0,0,0);
                a1 = __builtin_amdgcn_mfma_i32_16x16x64_i8(qfh[kc], blv, a1, 0,0,0);
                a0 = __builtin_amdgcn_mfma_i32_16x16x64_i8(qfl[kc], blv, a0, 0,0,0);
            }
            int st = ch*2 + i;
            #pragma unroll
            for (int r=0;r<4;r++)
                scv[st][r] = (a2[r]<<8) + (a1[r]<<4) + a0[r];
        }
    }

    // ================= softmax (log2 domain, hw exp) =================
    // CS2 = f32(2^-14/sqrt(128)) * log2(e): exp2((s-smax)*CS2) == exp((s-smax)*CS)
    const float CS2 = (float)(6.103515625e-05 / 11.313708498984760390566
                              * 1.4426950408889634074);
    float mx[4];
    #pragma unroll
    for (int r=0;r<4;r++){
        float m_ = -3.0e38f;
        #pragma unroll
        for (int st=0;st<16;st++){
            float f = (float)scv[st][r] * CS2;
            scv[st][r] = __float_as_int(f);        // keep scaled logit, avoid re-cvt
            m_ = fmaxf(m_, f);
        }
        #pragma unroll
        for (int o=8;o>0;o>>=1) m_ = fmaxf(m_, __shfl_xor(m_, o));
        mx[r] = m_;
    }
    if (ln == 0){
        #pragma unroll
        for (int r=0;r<4;r++) red[w*16 + qd4*4 + r] = mx[r];
    }
    __syncthreads();
    float sm[4];
    #pragma unroll
    for (int r=0;r<4;r++){
        float m_ = fmaxf(fmaxf(red[qd4*4+r], red[16+qd4*4+r]),
                         fmaxf(red[32+qd4*4+r], red[48+qd4*4+r]));
        float s_ = 0.f;
        #pragma unroll
        for (int st=0;st<16;st++){
            float t = __int_as_float(scv[st][r]) - m_;   // <= 0
            float e;
            asm("v_exp_f32 %0, %1" : "=v"(e) : "v"(t));  // 2^t, denorm->0 is fine
            scv[st][r] = __float_as_int(e);
            s_ += e;
        }
        #pragma unroll
        for (int o=8;o>0;o>>=1) s_ += __shfl_xor(s_, o);
        sm[r] = s_;
    }
    if (ln == 0){
        #pragma unroll
        for (int r=0;r<4;r++) red[64 + w*16 + qd4*4 + r] = sm[r];
    }
    __syncthreads();
    float inv14[4];
    #pragma unroll
    for (int r=0;r<4;r++){
        float s_ = red[64+qd4*4+r] + red[80+qd4*4+r] + red[96+qd4*4+r] + red[112+qd4*4+r];
        inv14[r] = 16384.0f / s_;      // one IEEE div per row
    }

    // ---- pass A: raw fixed-point probs (<=16384) to LDS as u16 ----
    #pragma unroll
    for (int st=0;st<16;st++){
        int colb = (st>>1)*128 + (w*2+(st&1))*16;
        #pragma unroll
        for (int r=0;r<4;r++){
            int val = (int)rintf(__int_as_float(scv[st][r]) * inv14[r]);
            int row = qd4*4 + r;
            int col = colb + ln;
            int gs  = (col>>3) ^ (row&7);
            rbuf[row*RST + gs*8 + (col&7)] = (unsigned short)val;
        }
    }
    __syncthreads();

    // ---- pass B: per-granule group-of-8 po2 requant, in place (u16 -> bf16) ----
    // granule == quant group == phase-2 A-fragment: no cross-lane reduce needed.
    {
        const int prow = tid >> 4;        // 0..15: rbuf row
        const int pc   = tid & 15;
        unsigned short* rp = rbuf + prow*RST;
        #pragma unroll
        for (int i=0;i<8;i++){
            const int cg  = pc + 16*i;                    // col granule 0..127
            const int off = (cg ^ (prow & 7)) << 3;       // swizzled, u16 units
            v8s v = *(const v8s*)(rp + off);
            int g01 = max((int)v[0], (int)v[1]), g23 = max((int)v[2], (int)v[3]);
            int g45 = max((int)v[4], (int)v[5]), g67 = max((int)v[6], (int)v[7]);
            int gmax = max(max(g01, g23), max(g45, g67));
            int gi = max(gmax, 1);
            int x  = gi - 1;
            int e2 = 31 - __clz(x | 255);
            int sh = (e2 - 7) + ((x >> (e2 - 7)) == 255); // clip(ceil(log2(gi/255)),0,)
            float isc = __int_as_float((127 - sh) << 23); // exact 2^-sh
            v8s o;
            #pragma unroll
            for (int j=0;j<8;j++){
                float rq = fminf(rintf((float)(int)v[j] * isc), 255.0f); // half-even
                o[j] = (short)bf16_of_int(((int)rq) << sh);  // r<=32640, 8 sig bits
            }
            *(v8s*)(rp + off) = o;
        }
    }
    __syncthreads();

    // ================= phase 2: out = r @ vt^T (bf16 MFMA, barrier-free) =================
    const v4i* vb = (const v4i*)(vd + (size_t)bh*VD_BH);
    v4f acc0{0,0,0,0}, acc1{0,0,0,0};
    #pragma unroll 4
    for (int kb=0; kb<32; ++kb){
        // A frag: r[t=ln][s = kb*32 + qd4*8 + j], 8 bf16 = one b128 from LDS
        v8s af = *(const v8s*)(rbuf + ln*RST + (((kb*4+qd4) ^ (ln&7))<<3));
        v4i b0, b1;
        if (PK){
            b0 = vb[(kb*8 + w*2    )*64 + lane];
            b1 = vb[(kb*8 + w*2 + 1)*64 + lane];
        } else {
            #pragma unroll
            for (int i=0;i<2;i++){
                int chan = (w*2+i)*16 + ln;
                const int* vp = vt_q + (size_t)(bh*HCN + chan)*SN + kb*32 + qd4*8;
                int s = vt_s[(bh*HCN + chan)*128 + kb*4 + qd4];
                unsigned wd[4];
                #pragma unroll
                for (int j=0;j<4;j++){
                    int a = vp[j*2]   << s;
                    int b = vp[j*2+1] << s;
                    wd[j] = (unsigned)bf16_of_int(a) | ((unsigned)bf16_of_int(b)<<16);
                }
                v4i t{(int)wd[0],(int)wd[1],(int)wd[2],(int)wd[3]};
                if (i==0) b0 = t; else b1 = t;
            }
        }
        v8s bs0, bs1;
        memcpy(&bs0, &b0, 16);
        memcpy(&bs1, &b1, 16);
        acc0 = __builtin_amdgcn_mfma_f32_16x16x32_bf16(af, bs0, acc0, 0,0,0);
        acc1 = __builtin_amdgcn_mfma_f32_16x16x32_bf16(af, bs1, acc1, 0,0,0);
    }
    #pragma unroll
    for (int r=0;r<4;r++){
        size_t o = (size_t)(bh*TN + t0 + qd4*4 + r)*HCN + (w*2)*16 + ln;
        out[o]      = (int)rintf(acc0[r]);
        out[o + 16] = (int)rintf(acc1[r]);
    }
}

extern "C" void kernel_launch(void* const* d_in, const int* in_sizes, int n_in,
                              void* d_out, int out_size, void* d_ws, size_t ws_size,
                              hipStream_t stream) {
    const int* q_q  = (const int*)d_in[0];
    const int* q_s  = (const int*)d_in[1];
    const int* k_q  = (const int*)d_in[2];
    const int* k_s  = (const int*)d_in[3];
    const int* vt_q = (const int*)d_in[4];
    const int* vt_s = (const int*)d_in[5];
    int* out = (int*)d_out;

    unsigned char* kd = (unsigned char*)d_ws;
    unsigned char* vd = kd + (size_t)BHN*KD_BH;

    if (ws_size >= WS_NEED){
        // 12288 wave-tasks (4096 kd + 8192 vd), 4 waves/block
        digitize<<<dim3(3072), 256, 0, stream>>>(k_q,k_s,vt_q,vt_s, kd,vd);
        mha_mfma<true><<<dim3(2048), 256, 0, stream>>>(
            q_q,q_s,k_q,k_s,vt_q,vt_s, kd,vd, out);
    } else {
        mha_mfma<false><<<dim3(2048), 256, 0, stream>>>(
            q_q,q_s,k_q,k_s,vt_q,vt_s, kd,vd, out);
    }
}

// Round 2
// 151.768 us; speedup vs baseline: 1.1363x; 1.0307x over previous
//
#include <hip/hip_runtime.h>
#include <string.h>

// Integer-quantized MHA. Phase 1: exact-int i8 K=64 MFMA digit GEMM, TRANSPOSED
// (C[s][t] via mfma(K,Q)) so the S-axis quant group is lane-local. Phase 2:
// native bf16 MFMA (r_q<=255, vt mantissa 8-bit -> exact products).
// R8 changes vs R7 (156us total, mha=68us, VALUBusy 47%):
//  - phase-1 operand swap: thread holds s = tile*16+qd4*4+r for ONE t=ln.
//    Group-of-8 requant = own-4 max + one shfl_xor(16); pass A (64 ds_write_b16)
//    and pass B (16 b128 + ~490 VALU) deleted, one barrier removed.
//  - softmax reductions: in-thread trees + shfl_xor(16/32) + cross-wave LDS;
//    one div per thread (was 4).
//  - requant in registers: fmin clamp dropped (gmax<=255<<sh by construction),
//    bf16 = bits(rq * 2^sh)>>16, v_perm pack, ONE b64 rbuf store per tile.
//  - rbuf swizzle gains row-bit3 XOR (both sides) to kill ln/ln+8 bank alias.
// B=2,H=16 (BH=32), T=S=1024, HC=128, G=8. Output int32.

typedef int   v4i __attribute__((ext_vector_type(4)));
typedef float v4f __attribute__((ext_vector_type(4)));
typedef short v8s __attribute__((ext_vector_type(8)));
typedef unsigned v2u __attribute__((ext_vector_type(2)));

#define BHN 32
#define TN  1024
#define SN  1024
#define HCN 128
#define TT  16
#define RST 1032               // rbuf row stride (u16): 2064 B == 16 mod 128 -> conflict-free
#define KD_BH 262144           // 8 chunks * 32 KB (2 planes, fragment-ordered)
#define VD_BH 262144           // 32 kb * 8 n * 64 lanes * 16 B (bf16 frags)
#define WS_NEED ((size_t)BHN*(KD_BH+VD_BH))   // 16 MB

__device__ __forceinline__ unsigned pack_b(int b0,int b1,int b2,int b3){
    return (unsigned)((b0&255)|((b1&255)<<8)|((b2&255)<<16)|((b3&255)<<24));
}

// digitize 16 consecutive dequantized ints (2 scale groups) into hi/lo i8 digit vectors
__device__ __forceinline__ void dig16(const int* __restrict__ p, int s0, int s1,
                                      v4i& hi, v4i& lo){
    #pragma unroll
    for (int wi=0; wi<4; ++wi){
        v4i m = *(const v4i*)(p + wi*4);
        int s = (wi<2) ? s0 : s1;
        int d0=m[0]<<s, d1=m[1]<<s, d2=m[2]<<s, d3=m[3]<<s;
        hi[wi] = (int)pack_b(d0>>4,d1>>4,d2>>4,d3>>4);
        lo[wi] = (int)pack_b(d0&15,d1&15,d2&15,d3&15);
    }
}

__device__ __forceinline__ unsigned short bf16_of_int(int v){
    return (unsigned short)(__float_as_uint((float)v) >> 16);   // exact: <=8 sig bits
}

// ---------------- pre-pass (gather form: coalesced stores) ----------------
// kd: per bh, [ch(8)][n(8)][kc(2)][plane(2:hi,lo)][lane64][16B]
// vd: per bh, [kb(32)][n(8)][lane64][16B]  (8 bf16 per lane)
// One wave per fragment tile: wave stores lane*16 -> contiguous 1KB per store.
// Tasks: 0..4095 = kd (bh*128+ch*16+n*2+kc); 4096..12287 = vd (bh*256+kb*8+n).
__global__ __launch_bounds__(256) void digitize(
    const int* __restrict__ k_q, const int* __restrict__ k_s,
    const int* __restrict__ vt_q, const int* __restrict__ vt_s,
    unsigned char* __restrict__ kd, unsigned char* __restrict__ vd)
{
    const int w    = threadIdx.x >> 6;
    const int lane = threadIdx.x & 63;
    const int l15  = lane & 15;
    const int task = blockIdx.x*4 + w;
    if (task < 4096){
        const int kc = task & 1, n = (task>>1)&7, ch = (task>>4)&7, bh = task>>7;
        const int q4   = lane >> 4;
        const int srow = bh*SN + ch*128 + n*16 + l15;
        const int gb   = srow*16 + kc*8 + q4*2;
        v4i hi, lo;
        dig16(k_q + (size_t)srow*HCN + kc*64 + q4*16, k_s[gb], k_s[gb+1], hi, lo);
        size_t base = (size_t)bh*KD_BH + (size_t)(ch*32768 + n*4096 + kc*2048 + lane*16);
        *(v4i*)(kd + base)        = hi;     // 1KB coalesced wave store (hi plane)
        *(v4i*)(kd + base + 1024) = lo;     // 1KB coalesced wave store (lo plane)
    } else {
        const int t  = task - 4096;
        const int n  = t & 7, kb = (t>>3)&31, bh = t>>8;
        const int sub = lane >> 4;                 // s-quad within fragment
        const int row = bh*HCN + n*16 + l15;       // vt channel row
        const int* vp = vt_q + (size_t)row*SN + kb*32 + sub*8;
        const int s   = vt_s[row*128 + kb*4 + sub];
        unsigned wds[4];
        #pragma unroll
        for (int j=0;j<4;j++){
            int a = vp[j*2]   << s;
            int b = vp[j*2+1] << s;
            wds[j] = (unsigned)bf16_of_int(a) | ((unsigned)bf16_of_int(b) << 16);
        }
        size_t base = (size_t)bh*VD_BH + (size_t)(((kb*8 + n)*64 + lane)*16);
        *(v4i*)(vd + base) = v4i{(int)wds[0],(int)wds[1],(int)wds[2],(int)wds[3]};
    }
}

// ---------------- main fused kernel ----------------
template<bool PK>
__global__ __launch_bounds__(256,4) void mha_mfma(
    const int* __restrict__ q_q, const int* __restrict__ q_s,
    const int* __restrict__ k_q, const int* __restrict__ k_s,
    const int* __restrict__ vt_q, const int* __restrict__ vt_s,
    const unsigned char* __restrict__ kd, const unsigned char* __restrict__ vd,
    int* __restrict__ out)
{
    __shared__ __align__(16) unsigned short rbuf[16*RST];  // 33 KB r values, granule swizzle
    __shared__ float red[128];                             // cross-wave softmax reductions

    const int tid  = threadIdx.x;
    const int ln   = tid & 15;
    const int qd4  = (tid >> 4) & 3;
    const int w    = tid >> 6;
    const int lane = tid & 63;
    // XCD-aware swizzle: each XCD's share covers only 4 bh -> digit images fit its L2.
    const int blk = blockIdx.x;
    const int bh  = ((blk>>9)<<3) | (blk&7);
    const int t0  = ((blk>>3)&63) * TT;

    // ---- Q fragments in registers (digitized in-reg from global); used as the
    // B operand in phase 1 (lane&15 = t), layout identical to the old A use. ----
    v4i qfh[2], qfl[2];
    {
        const int* qrow  = q_q + (size_t)(bh*TN + t0 + ln)*HCN;
        const int* qsrow = q_s + (size_t)(bh*TN + t0 + ln)*16;
        #pragma unroll
        for (int kc=0; kc<2; ++kc){
            int gi = kc*8 + qd4*2;
            dig16(qrow + kc*64 + qd4*16, qsrow[gi], qsrow[gi+1], qfh[kc], qfl[kc]);
        }
    }

    int scv[16][4];   // C[s][t]: s = (ch*8 + w*2 + i)*16 + qd4*4 + r, t = ln

    // ================= phase 1: QK^T scores, TRANSPOSED (barrier-free, exact int) =====
    const v4i* kb_ = (const v4i*)(kd + (size_t)bh*KD_BH);
    for (int ch=0; ch<8; ++ch){
        #pragma unroll
        for (int i=0;i<2;i++){
            const int n = w*2 + i;
            v4i a2{0,0,0,0}, a1{0,0,0,0}, a0{0,0,0,0};
            #pragma unroll
            for (int kc=0;kc<2;kc++){
                v4i bhv, blv;
                if (PK){
                    const v4i* tb = kb_ + (ch*8+n)*256 + kc*128 + lane;
                    bhv = tb[0];
                    blv = tb[64];
                } else {
                    int srow = bh*SN + ch*128 + n*16 + ln;
                    int cc   = kc*64 + qd4*16;
                    dig16(k_q + (size_t)srow*128 + cc,
                          k_s[srow*16 + (cc>>3)], k_s[srow*16 + (cc>>3) + 1], bhv, blv);
                }
                // A = K digits, B = Q digits  ->  C[s][t]
                a2 = __builtin_amdgcn_mfma_i32_16x16x64_i8(bhv, qfh[kc], a2, 0,0,0);
                a1 = __builtin_amdgcn_mfma_i32_16x16x64_i8(bhv, qfl[kc], a1, 0,0,0);
                a1 = __builtin_amdgcn_mfma_i32_16x16x64_i8(blv, qfh[kc], a1, 0,0,0);
                a0 = __builtin_amdgcn_mfma_i32_16x16x64_i8(blv, qfl[kc], a0, 0,0,0);
            }
            int st = ch*2 + i;
            #pragma unroll
            for (int r=0;r<4;r++)
                scv[st][r] = (a2[r]<<8) + (a1[r]<<4) + a0[r];
        }
    }

    // ================= softmax over s (log2 domain, hw exp) =================
    // All 64 of this thread's elements belong to ONE output row t=ln.
    const float CS2 = (float)(6.103515625e-05 / 11.313708498984760390566
                              * 1.4426950408889634074);
    {
        float m0=-3.0e38f, m1=-3.0e38f, m2=-3.0e38f, m3=-3.0e38f;
        #pragma unroll
        for (int st=0;st<16;st++){
            float f0 = (float)scv[st][0]*CS2; scv[st][0]=__float_as_int(f0); m0=fmaxf(m0,f0);
            float f1 = (float)scv[st][1]*CS2; scv[st][1]=__float_as_int(f1); m1=fmaxf(m1,f1);
            float f2 = (float)scv[st][2]*CS2; scv[st][2]=__float_as_int(f2); m2=fmaxf(m2,f2);
            float f3 = (float)scv[st][3]*CS2; scv[st][3]=__float_as_int(f3); m3=fmaxf(m3,f3);
        }
        float m_ = fmaxf(fmaxf(m0,m1), fmaxf(m2,m3));
        m_ = fmaxf(m_, __shfl_xor(m_, 16));
        m_ = fmaxf(m_, __shfl_xor(m_, 32));
        if ((tid & 48) == 0) red[w*16 + ln] = m_;
    }
    __syncthreads();
    const float mrow = fmaxf(fmaxf(red[ln], red[16+ln]), fmaxf(red[32+ln], red[48+ln]));
    float inv14;
    {
        float s0=0.f, s1=0.f, s2=0.f, s3=0.f;
        #pragma unroll
        for (int st=0;st<16;st++){
            #pragma unroll
            for (int r=0;r<4;r++){
                float t_ = __int_as_float(scv[st][r]) - mrow;   // <= 0
                float e;
                asm("v_exp_f32 %0, %1" : "=v"(e) : "v"(t_));    // 2^t
                scv[st][r] = __float_as_int(e);
                if (r==0) s0 += e; else if (r==1) s1 += e; else if (r==2) s2 += e; else s3 += e;
            }
        }
        float s_ = (s0+s1) + (s2+s3);
        s_ += __shfl_xor(s_, 16);
        s_ += __shfl_xor(s_, 32);
        if ((tid & 48) == 0) red[64 + w*16 + ln] = s_;
    }
    __syncthreads();
    {
        float sum = red[64+ln] + red[80+ln] + red[96+ln] + red[112+ln];
        inv14 = 16384.0f / sum;        // one IEEE div per thread
    }

    // ======== group-of-8 po2 requant, fully in registers -> b64 rbuf stores ========
    // granule = thread's 4 s-values + partner at lane^16. gmax <= 255<<sh by the
    // sh formula, so no 255-clamp is needed.
    {
        unsigned short* rp = rbuf + ln*RST;
        const int swzr = (ln & 7) ^ ((ln & 8) >> 1);   // row XOR key (kills ln/ln+8 alias)
        const int cbase = (w*2)*16 + qd4*4;
        #pragma unroll
        for (int st=0;st<16;st++){
            float v0 = rintf(__int_as_float(scv[st][0]) * inv14);
            float v1 = rintf(__int_as_float(scv[st][1]) * inv14);
            float v2 = rintf(__int_as_float(scv[st][2]) * inv14);
            float v3 = rintf(__int_as_float(scv[st][3]) * inv14);
            float g = fmaxf(fmaxf(v0,v1), fmaxf(v2,v3));
            g = fmaxf(g, __shfl_xor(g, 16));            // partner half of the granule
            int gi = max((int)g, 1);
            int x  = gi - 1;
            int e2 = 31 - __clz(x | 255);
            int sh = (e2 - 7) + ((x >> (e2 - 7)) == 255); // clip(ceil(log2(gi/255)),0,)
            float isc = __int_as_float((127 - sh) << 23); // exact 2^-sh
            float fsc = __int_as_float((127 + sh) << 23); // exact 2^sh
            unsigned b0 = __float_as_uint(rintf(v0*isc) * fsc);  // r = rq<<sh, 8 sig bits
            unsigned b1 = __float_as_uint(rintf(v1*isc) * fsc);
            unsigned b2 = __float_as_uint(rintf(v2*isc) * fsc);
            unsigned b3 = __float_as_uint(rintf(v3*isc) * fsc);
            unsigned w0 = __builtin_amdgcn_perm(b1, b0, 0x07060302u); // {bf16(v0),bf16(v1)}
            unsigned w1 = __builtin_amdgcn_perm(b3, b2, 0x07060302u);
            int c0 = ((st>>1)*128) + cbase + ((st&1)*16);  // col of v0 (4-aligned, &7 in {0,4})
            int gs = (c0>>3) ^ swzr;
            *(v2u*)(rp + gs*8 + (c0&7)) = v2u{w0, w1};     // one b64 store per tile
        }
    }
    __syncthreads();

    // ================= phase 2: out = r @ vt^T (bf16 MFMA, barrier-free) =================
    const v4i* vb = (const v4i*)(vd + (size_t)bh*VD_BH);
    const unsigned short* rp2 = rbuf + ln*RST;
    const int swzr2 = (ln & 7) ^ ((ln & 8) >> 1);
    v4f acc0{0,0,0,0}, acc1{0,0,0,0};
    #pragma unroll 4
    for (int kb=0; kb<32; ++kb){
        // A frag: r[t=ln][s = kb*32 + qd4*8 + j], 8 bf16 = one b128 from LDS
        v8s af = *(const v8s*)(rp2 + (((kb*4+qd4) ^ swzr2) << 3));
        v4i b0, b1;
        if (PK){
            b0 = vb[(kb*8 + w*2    )*64 + lane];
            b1 = vb[(kb*8 + w*2 + 1)*64 + lane];
        } else {
            #pragma unroll
            for (int i=0;i<2;i++){
                int chan = (w*2+i)*16 + ln;
                const int* vp = vt_q + (size_t)(bh*HCN + chan)*SN + kb*32 + qd4*8;
                int s = vt_s[(bh*HCN + chan)*128 + kb*4 + qd4];
                unsigned wd[4];
                #pragma unroll
                for (int j=0;j<4;j++){
                    int a = vp[j*2]   << s;
                    int b = vp[j*2+1] << s;
                    wd[j] = (unsigned)bf16_of_int(a) | ((unsigned)bf16_of_int(b)<<16);
                }
                v4i t{(int)wd[0],(int)wd[1],(int)wd[2],(int)wd[3]};
                if (i==0) b0 = t; else b1 = t;
            }
        }
        v8s bs0, bs1;
        memcpy(&bs0, &b0, 16);
        memcpy(&bs1, &b1, 16);
        acc0 = __builtin_amdgcn_mfma_f32_16x16x32_bf16(af, bs0, acc0, 0,0,0);
        acc1 = __builtin_amdgcn_mfma_f32_16x16x32_bf16(af, bs1, acc1, 0,0,0);
    }
    #pragma unroll
    for (int r=0;r<4;r++){
        size_t o = (size_t)(bh*TN + t0 + qd4*4 + r)*HCN + (w*2)*16 + ln;
        out[o]      = (int)rintf(acc0[r]);
        out[o + 16] = (int)rintf(acc1[r]);
    }
}

extern "C" void kernel_launch(void* const* d_in, const int* in_sizes, int n_in,
                              void* d_out, int out_size, void* d_ws, size_t ws_size,
                              hipStream_t stream) {
    const int* q_q  = (const int*)d_in[0];
    const int* q_s  = (const int*)d_in[1];
    const int* k_q  = (const int*)d_in[2];
    const int* k_s  = (const int*)d_in[3];
    const int* vt_q = (const int*)d_in[4];
    const int* vt_s = (const int*)d_in[5];
    int* out = (int*)d_out;

    unsigned char* kd = (unsigned char*)d_ws;
    unsigned char* vd = kd + (size_t)BHN*KD_BH;

    if (ws_size >= WS_NEED){
        // 12288 wave-tasks (4096 kd + 8192 vd), 4 waves/block
        digitize<<<dim3(3072), 256, 0, stream>>>(k_q,k_s,vt_q,vt_s, kd,vd);
        mha_mfma<true><<<dim3(2048), 256, 0, stream>>>(
            q_q,q_s,k_q,k_s,vt_q,vt_s, kd,vd, out);
    } else {
        mha_mfma<false><<<dim3(2048), 256, 0, stream>>>(
            q_q,q_s,k_q,k_s,vt_q,vt_s, kd,vd, out);
    }
}